// Round 1
// 1127.429 us; speedup vs baseline: 1.0018x; 1.0018x over previous
//
#include <hip/hip_runtime.h>

// out[o] = act( sum_k iv[k] * W[in_idx[k], out_idx[o]] + bias[out_idx[o]] )
// act: 0=identity, 1=relu, 2=softsign
//
// Shape (reference): N=16384, num_in=1024, num_out=256.
// Unique W bytes needed: 1 MB (16 MB at 64B-line granularity) -> the kernel is
// a latency-bound gather, ~5 us floor. Structure: one block per output,
// 1024 threads (16 waves), ONE W-load per thread -> single memory round trip
// on the critical path (the old 256-thread version had a runtime-trip-count
// loop = up to 4 serialized round trips).

__global__ __launch_bounds__(1024) void sparse_gemv_kernel(
    const float* __restrict__ iv,      // [num_in]
    const float* __restrict__ W,       // [N, N] row-major
    const float* __restrict__ bias,    // [N]
    const int*   __restrict__ act,     // [N]
    const int*   __restrict__ in_idx,  // [num_in]
    const int*   __restrict__ out_idx, // [num_out]
    float*       __restrict__ out,     // [num_out]
    int N, int num_in)
{
    const int o   = blockIdx.x;
    const int j   = out_idx[o];
    const int tid = threadIdx.x;

    // One element per thread in the reference shape (num_in == blockDim);
    // stride loop keeps it general. Loads across iterations are independent.
    float sum = 0.0f;
    for (int k = tid; k < num_in; k += blockDim.x) {
        const int row = in_idx[k];                 // L2-resident after block 0
        sum += iv[k] * W[(size_t)row * (size_t)N + (size_t)j];
    }

    // Wave (64-lane) shuffle reduction.
    #pragma unroll
    for (int off = 32; off > 0; off >>= 1)
        sum += __shfl_down(sum, off, 64);

    // Cross-wave reduction: 16 waves in a 1024-thread block.
    __shared__ float wsum[16];
    const int wave = tid >> 6;
    if ((tid & 63) == 0) wsum[wave] = sum;
    __syncthreads();

    if (tid == 0) {
        const int nw = (int)((blockDim.x + 63) >> 6);
        float t = bias[j];
        #pragma unroll 4
        for (int w = 0; w < nw; ++w) t += wsum[w];
        const int a = act[j];
        const float r = fmaxf(t, 0.0f);
        const float s = t / (1.0f + fabsf(t));
        out[o] = (a == 1) ? r : ((a == 2) ? s : t);
    }
}

extern "C" void kernel_launch(void* const* d_in, const int* in_sizes, int n_in,
                              void* d_out, int out_size, void* d_ws, size_t ws_size,
                              hipStream_t stream) {
    const float* iv      = (const float*)d_in[0];  // input_values   [num_in]
    const float* W       = (const float*)d_in[1];  // weight_matrix  [N*N]
    const float* bias    = (const float*)d_in[2];  // biases         [N]
    const int*   act     = (const int*)  d_in[3];  // act_ids        [N]
    const int*   in_idx  = (const int*)  d_in[4];  // input_indices  [num_in]
    const int*   out_idx = (const int*)  d_in[5];  // output_indices [num_out]
    float*       out     = (float*)d_out;

    const int num_in  = in_sizes[0];
    const int N       = in_sizes[2];   // biases length
    const int num_out = out_size;

    sparse_gemv_kernel<<<num_out, 1024, 0, stream>>>(
        iv, W, bias, act, in_idx, out_idx, out, N, num_in);
}